// Round 1
// baseline (1191.912 us; speedup 1.0000x reference)
//
#include <hip/hip_runtime.h>
#include <stdint.h>

#define TOPK 20
#define BLK 256
#define CAP 4096
#define DELTA 2.0f
#define LSTRIDE 21
#define L2E 1.4426950408889634f
#define IGNORE_INDEX (-100)

__device__ __forceinline__ unsigned fkey(float x) {
  unsigned b = __float_as_uint(x);
  return (b & 0x80000000u) ? ~b : (b | 0x80000000u);
}
__device__ __forceinline__ float funkey(unsigned k) {
  unsigned b = (k & 0x80000000u) ? (k & 0x7FFFFFFFu) : ~k;
  return __uint_as_float(b);
}

// online logsumexp state (natural log domain, exp via exp2)
struct LSE { float m; float l; };
__device__ __forceinline__ void lse_up(LSE& s, float x) {
  if (x > s.m) { s.l *= exp2f((s.m - x) * L2E); s.m = x; }
  s.l += exp2f((x - s.m) * L2E);
}

// sorted-descending top-20 insert (fully unrolled, registers only)
__device__ __forceinline__ void ins20(float (&tv)[TOPK], float c) {
  if (c > tv[TOPK - 1]) {
#pragma unroll
    for (int j = 0; j < TOPK; ++j) {
      float hi = fmaxf(tv[j], c);
      c = fminf(tv[j], c);
      tv[j] = hi;
    }
  }
}

// merge two sorted-desc 20-lists (padded to 21 with -inf) -> top-20 into O
__device__ __forceinline__ void merge2(const float* A, const float* B, float* O) {
  int i = 1, j = 1;
  float a = A[0], b = B[0];
#pragma unroll
  for (int k = 0; k < TOPK; ++k) {
    if (a >= b) { O[k] = a; a = A[i]; ++i; }
    else        { O[k] = b; b = B[j]; ++j; }
  }
}

// merge 64 lists living in bufA (stride LSTRIDE, pad slot 20 = -inf).
// ALL 256 threads must call (contains barriers). Returns pointer to result list.
__device__ float* merge64(int tid, float* bufA, float* bufB) {
  float* srcb = bufA;
  float* dstb = bufB;
  for (int s = 32; s >= 1; s >>= 1) {
    __syncthreads();
    if (tid < s) {
      merge2(srcb + tid * LSTRIDE, srcb + (tid + s) * LSTRIDE, dstb + tid * LSTRIDE);
      dstb[tid * LSTRIDE + TOPK] = -INFINITY;
    }
    float* t = srcb; srcb = dstb; dstb = t;
  }
  __syncthreads();
  return srcb;
}

__global__ __launch_bounds__(BLK) void eaft_ce_kernel(
    const float* __restrict__ src, const int* __restrict__ tgt,
    float* __restrict__ acc, int V) {
  __shared__ float s_cand[CAP];
  __shared__ float s_bufA[64 * LSTRIDE];
  __shared__ float s_bufB[64 * LSTRIDE];
  __shared__ float s_m[BLK];
  __shared__ float s_l[BLK];
  __shared__ unsigned s_maxkey;
  __shared__ int s_cnt;
  __shared__ int s_slow;

  const int tid = threadIdx.x;
  const int row = blockIdx.x;
  if (tid == 0) { s_maxkey = 0u; s_cnt = 0; s_slow = 0; }
  __syncthreads();

  const size_t rowbase = (size_t)row * (size_t)V;
  const float* arow = src + rowbase;
  const int mis = (int)(rowbase & 3);
  const int head = (4 - mis) & 3;
  const float4* vp = (const float4*)(arow + head);
  const int nvec = (V - head) >> 2;
  const int tail = V - head - (nvec << 2);

  LSE st; st.m = -INFINITY; st.l = 0.f;
  float lmax = -INFINITY;  // lane's view of the block running max

  // ---------- peel: first vec batch + head/tail scalars (prime block max) ----------
  float4 pv = make_float4(-INFINITY, -INFINITY, -INFINITY, -INFINITY);
  if (tid < nvec) pv = vp[tid];
  float ex = -INFINITY;
  if (tid < head) ex = arow[tid];
  else if (tid >= 64 && tid < 64 + tail) ex = arow[head + (nvec << 2) + (tid - 64)];

  {
    float vals[5] = {pv.x, pv.y, pv.z, pv.w, ex};
#pragma unroll
    for (int q = 0; q < 5; ++q) {
      float x = vals[q];
      if (x != -INFINITY) {
        lse_up(st, x);
        if (x > lmax) { lmax = x; atomicMax(&s_maxkey, fkey(x)); }
      }
    }
  }
  __syncthreads();  // block max now primed with ~1024 samples

  // retroactive candidate test of peel elements
  {
    float bm = funkey(*(volatile unsigned*)&s_maxkey);
    if (bm > lmax) lmax = bm;
    float T = bm - DELTA;
    float vals[5] = {pv.x, pv.y, pv.z, pv.w, ex};
#pragma unroll
    for (int q = 0; q < 5; ++q) {
      float x = vals[q];
      if (x >= T) {
        int p = atomicAdd(&s_cnt, 1);
        if (p < CAP) s_cand[p] = x;
      }
    }
  }

  // ---------- main streaming loop ----------
  for (int i = BLK + tid; i < nvec; i += BLK) {
    float4 x4 = vp[i];
    unsigned k = *(volatile unsigned*)&s_maxkey;
    float bm = funkey(k);
    if (bm > lmax) lmax = bm;
    float T = bm - DELTA;
    float vv[4] = {x4.x, x4.y, x4.z, x4.w};
#pragma unroll
    for (int q = 0; q < 4; ++q) {
      float x = vv[q];
      lse_up(st, x);
      if (x > lmax) { lmax = x; atomicMax(&s_maxkey, fkey(x)); }
      if (x >= T) {
        int p = atomicAdd(&s_cnt, 1);
        if (p < CAP) s_cand[p] = x;
      }
    }
  }

  // ---------- block logsumexp reduction ----------
  s_m[tid] = st.m; s_l[tid] = st.l;
  __syncthreads();
  for (int s = BLK / 2; s > 0; s >>= 1) {
    if (tid < s) {
      float m1 = s_m[tid], l1 = s_l[tid];
      float m2 = s_m[tid + s], l2 = s_l[tid + s];
      float M = fmaxf(m1, m2);
      float w1 = (m1 > -INFINITY) ? l1 * exp2f((m1 - M) * L2E) : 0.f;
      float w2 = (m2 > -INFINITY) ? l2 * exp2f((m2 - M) * L2E) : 0.f;
      s_m[tid] = M; s_l[tid] = w1 + w2;
    }
    __syncthreads();
  }
  const float m_row = s_m[0];
  const float lse_row = m_row + logf(s_l[0]);

  // ---------- top-20 selection from candidates (wave 0 builds 64 lists) ----------
  const int cnt_raw = s_cnt;             // visible after reduction barriers
  const int C = cnt_raw < CAP ? cnt_raw : CAP;
  if (tid < 64) {
    float tv[TOPK];
#pragma unroll
    for (int j = 0; j < TOPK; ++j) tv[j] = -INFINITY;
    for (int i = tid; i < C; i += 64) ins20(tv, s_cand[i]);
#pragma unroll
    for (int j = 0; j < TOPK; ++j) s_bufA[tid * LSTRIDE + j] = tv[j];
    s_bufA[tid * LSTRIDE + TOPK] = -INFINITY;
  }
  float* R = merge64(tid, s_bufA, s_bufB);

  // ---------- verification; rare exact slow path ----------
  if (tid == 0)
    s_slow = (cnt_raw > CAP || R[TOPK - 1] < m_row - DELTA) ? 1 : 0;
  __syncthreads();

  if (s_slow) {
    float tv[TOPK];
#pragma unroll
    for (int j = 0; j < TOPK; ++j) tv[j] = -INFINITY;
    for (int e = tid; e < V; e += BLK) ins20(tv, arow[e]);
    for (int r = 0; r < 4; ++r) {
      __syncthreads();
      if ((tid >> 6) == r) {
        int lane = tid & 63;
#pragma unroll
        for (int j = 0; j < TOPK; ++j) s_bufA[lane * LSTRIDE + j] = tv[j];
        s_bufA[lane * LSTRIDE + TOPK] = -INFINITY;
      }
      float* Rr = merge64(tid, s_bufA, s_bufB);
      if (tid == 0) {
#pragma unroll
        for (int j = 0; j < TOPK; ++j) s_cand[r * LSTRIDE + j] = Rr[j];
        s_cand[r * LSTRIDE + TOPK] = -INFINITY;
      }
      __syncthreads();
    }
    if (tid == 0) {
      merge2(s_cand + 0 * LSTRIDE, s_cand + 1 * LSTRIDE, s_bufA);
      s_bufA[TOPK] = -INFINITY;
      merge2(s_cand + 2 * LSTRIDE, s_cand + 3 * LSTRIDE, s_bufA + LSTRIDE);
      s_bufA[LSTRIDE + TOPK] = -INFINITY;
      merge2(s_bufA, s_bufA + LSTRIDE, s_bufB);
    }
  }
  __syncthreads();

  // ---------- entropy weight + loss contribution (thread 0) ----------
  if (tid == 0) {
    const float* W = s_slow ? s_bufB : R;
    int t = tgt[row];
    if (t != IGNORE_INDEX) {
      float tl = arow[t];
      float loss = lse_row - tl;
      float m0 = W[0];
      float S1 = 0.f, Sv = 0.f;
#pragma unroll
      for (int k2 = 0; k2 < TOPK; ++k2) {
        float v = W[k2];
        float e = exp2f((v - m0) * L2E);
        S1 += e;
        Sv += v * e;
      }
      float ent = (m0 + logf(S1)) - Sv / S1;
      float w = ent * (1.0f / 3.0f);
      atomicAdd(&acc[0], w * loss);
      atomicAdd(&acc[1], 1.0f);
    }
  }
}

__global__ void finalize_kernel(const float* __restrict__ acc, float* __restrict__ out) {
  out[0] = acc[0] / acc[1];
}

extern "C" void kernel_launch(void* const* d_in, const int* in_sizes, int n_in,
                              void* d_out, int out_size, void* d_ws, size_t ws_size,
                              hipStream_t stream) {
  const float* src = (const float*)d_in[0];
  const int* tgt = (const int*)d_in[1];
  const int NV = in_sizes[0];
  const int n = in_sizes[1];
  const int V = NV / n;
  float* ws = (float*)d_ws;
  hipMemsetAsync(ws, 0, 2 * sizeof(float), stream);
  eaft_ce_kernel<<<n, BLK, 0, stream>>>(src, tgt, ws, V);
  finalize_kernel<<<1, 1, 0, stream>>>(ws, (float*)d_out);
}